// Round 1
// baseline (583.597 us; speedup 1.0000x reference)
//
#include <hip/hip_runtime.h>
#include <math.h>

#define HH 256
#define WW 256
#define HWSZ (HH * WW)
#define KE 4096
#define NSLICE 16

// ---------------------------------------------------------------------------
// Edge predicate: pixel is an edge iff mask(pixel)=1 and some in-bounds 3x3
// neighbor has mask=0.  (min-pool with +inf padding => padding never creates
// edges; mask==0 center is never an edge.)
// ---------------------------------------------------------------------------
__device__ __forceinline__ bool is_edge(const float* __restrict__ img, int h, int w) {
    float v = img[h * WW + w];
    if (!(v > 0.5f)) return false;
#pragma unroll
    for (int dh = -1; dh <= 1; ++dh) {
        int hh = h + dh;
        if (hh < 0 || hh >= HH) continue;
#pragma unroll
        for (int dw = -1; dw <= 1; ++dw) {
            int ww2 = w + dw;
            if (ww2 < 0 || ww2 >= WW) continue;
            if (!(img[hh * WW + ww2] > 0.5f)) return true;
        }
    }
    return false;
}

// ---------------------------------------------------------------------------
// Kernel A: per (tensor, slice) ordered compaction of edge coordinates.
// 32 blocks, 256 threads. Each iteration handles one image row; block-wide
// ordered prefix via ballot keeps row-major order (matches jnp.nonzero).
// Stores at most KE points; full count stored separately (divisor!).
// ---------------------------------------------------------------------------
__global__ void __launch_bounds__(256) edges_compact(
        const float* __restrict__ gth, const float* __restrict__ pred,
        float2* __restrict__ gpts, float2* __restrict__ ppts,
        int* __restrict__ gcnt, int* __restrict__ pcnt) {
    int b = blockIdx.x;               // 0..31
    int tensor = b >> 4;              // 0 = gth, 1 = pred
    int slice = b & 15;
    const float* img = (tensor ? pred : gth) + slice * HWSZ;
    float2* pts = (tensor ? ppts : gpts) + slice * KE;
    int* cnt = (tensor ? pcnt : gcnt) + slice;

    __shared__ int wcnt[4];
    int tid = threadIdx.x;
    int lane = tid & 63;
    int wave = tid >> 6;
    int base = 0;
    for (int row = 0; row < HH; ++row) {
        bool e = is_edge(img, row, tid);
        unsigned long long bal = __ballot(e);
        if (lane == 0) wcnt[wave] = __popcll(bal);
        __syncthreads();
        int off = 0;
        for (int i = 0; i < wave; ++i) off += wcnt[i];
        int total = wcnt[0] + wcnt[1] + wcnt[2] + wcnt[3];
        int rank = __popcll(bal & ((1ull << lane) - 1ull));
        int pos = base + off + rank;
        if (e && pos < KE) pts[pos] = make_float2((float)row, (float)tid);
        base += total;
        __syncthreads();   // wcnt reused next row
    }
    if (tid == 0) *cnt = base;
}

// ---------------------------------------------------------------------------
// Kernel B: for each (slice, direction, query-chunk) block: stage target
// points in LDS, each thread computes min squared distance for one query
// point, sqrt at the end, deterministic block tree-sum -> one partial.
// If target set empty and query valid: sum becomes +inf (matches reference,
// slice is discarded in finalize anyway since a count is 0).
// ---------------------------------------------------------------------------
__global__ void __launch_bounds__(256) mindist(
        const float2* __restrict__ gpts, const float2* __restrict__ ppts,
        const int* __restrict__ gcnt, const int* __restrict__ pcnt,
        float* __restrict__ gpart, float* __restrict__ ppart) {
    int b = blockIdx.x;               // 0..511
    int slice = b >> 5;
    int dir = (b >> 4) & 1;           // 0: g->p, 1: p->g
    int qblk = b & 15;

    const float2* q = (dir ? ppts : gpts) + slice * KE;
    const float2* t = (dir ? gpts : ppts) + slice * KE;
    int qfull = dir ? pcnt[slice] : gcnt[slice];
    int tfull = dir ? gcnt[slice] : pcnt[slice];
    float* part = (dir ? ppart : gpart) + slice * 16 + qblk;

    __shared__ float2 tp[KE];
    __shared__ float red[256];
    int tc = min(tfull, KE);
    int qc = min(qfull, KE);
    int tid = threadIdx.x;

    for (int i = tid; i < tc; i += 256) tp[i] = t[i];
    __syncthreads();

    int qi = qblk * 256 + tid;
    float val = 0.0f;
    if (qi < qc) {
        float2 qp = q[qi];
        float dmin = INFINITY;
        for (int j = 0; j < tc; ++j) {
            float dy = qp.x - tp[j].x;
            float dx = qp.y - tp[j].y;
            float d2 = dy * dy + dx * dx;
            dmin = fminf(dmin, d2);
        }
        val = sqrtf(dmin);            // min of sqrt == sqrt of min
    }
    red[tid] = val;
    __syncthreads();
    for (int s = 128; s > 0; s >>= 1) {
        if (tid < s) red[tid] += red[tid + s];
        __syncthreads();
    }
    if (tid == 0) *part = red[0];
}

// ---------------------------------------------------------------------------
// Kernel C: fold partials -> per-slice ahd -> loss -> nanmean.
// Slice valid iff both counts > 0 (reference yields NaN otherwise).
// ---------------------------------------------------------------------------
__global__ void finalize(const int* __restrict__ gcnt, const int* __restrict__ pcnt,
                         const float* __restrict__ gpart, const float* __restrict__ ppart,
                         float* __restrict__ out) {
    float sum = 0.0f;
    int nvalid = 0;
    for (int s = 0; s < NSLICE; ++s) {
        int ng = gcnt[s];
        int np_ = pcnt[s];
        if (ng > 0 && np_ > 0) {
            float gs = 0.0f, ps = 0.0f;
            for (int k = 0; k < 16; ++k) {
                gs += gpart[s * 16 + k];
                ps += ppart[s * 16 + k];
            }
            float ahd = 0.5f * (gs / (float)ng + ps / (float)np_);
            sum += 1.0f - 1.0f / (1.0f + ahd);
            nvalid++;
        }
    }
    out[0] = nvalid ? (sum / (float)nvalid) : NAN;
}

// ---------------------------------------------------------------------------
// Workspace layout (bytes):
//   [0, 512K)        gpts: 16 slices x 4096 float2
//   [512K, 1M)       ppts: 16 slices x 4096 float2
//   [1M, 1M+64)      gcnt: 16 int
//   [1M+64, 1M+128)  pcnt: 16 int
//   [1M+128, +1K)    gpart: 16 x 16 float
//   [1M+1152, +1K)   ppart: 16 x 16 float
// ---------------------------------------------------------------------------
extern "C" void kernel_launch(void* const* d_in, const int* in_sizes, int n_in,
                              void* d_out, int out_size, void* d_ws, size_t ws_size,
                              hipStream_t stream) {
    const float* gth = (const float*)d_in[0];
    const float* pred = (const float*)d_in[1];
    float* out = (float*)d_out;
    char* ws = (char*)d_ws;

    float2* gpts = (float2*)(ws);
    float2* ppts = (float2*)(ws + 524288);
    int* gcnt = (int*)(ws + 1048576);
    int* pcnt = (int*)(ws + 1048576 + 64);
    float* gpart = (float*)(ws + 1048576 + 128);
    float* ppart = (float*)(ws + 1048576 + 128 + 1024);

    edges_compact<<<32, 256, 0, stream>>>(gth, pred, gpts, ppts, gcnt, pcnt);
    mindist<<<512, 256, 0, stream>>>(gpts, ppts, gcnt, pcnt, gpart, ppart);
    finalize<<<1, 1, 0, stream>>>(gcnt, pcnt, gpart, ppart, out);
}

// Round 2
// 78.638 us; speedup vs baseline: 7.4214x; 7.4214x over previous
//
#include <hip/hip_runtime.h>
#include <math.h>

#define HH 256
#define WW 256
#define HWSZ (HH * WW)
#define KE 4096
#define NSLICE 16

typedef unsigned long long u64;

// ---------------------------------------------------------------------------
// Kernel 1: binarize + bit-pack. One block per image row (2 tensors x 16
// slices x 256 rows = 8192 blocks). Lane i thresholds pixel col=tid; ballot
// packs 64 cols -> one u64 word. bm layout: [tensor][slice][row][word(4)].
// ---------------------------------------------------------------------------
__global__ void __launch_bounds__(256) binarize_pack(
        const float* __restrict__ gth, const float* __restrict__ pred,
        u64* __restrict__ bm) {
    int b = blockIdx.x;                 // tensor*4096 + slice*256 + row
    int tensor = b >> 12;
    int sr = b & 4095;                  // slice*256 + row
    const float* img = tensor ? pred : gth;
    float v = img[sr * WW + threadIdx.x];
    u64 bal = __ballot(v > 0.5f);
    int lane = threadIdx.x & 63;
    int wave = threadIdx.x >> 6;
    if (lane == 0) bm[(size_t)b * 4 + wave] = bal;
}

// ---------------------------------------------------------------------------
// Kernel 2: bitwise edge detect + ordered compaction. 32 blocks (tensor,
// slice), thread = row. Erosion (min-pool, +inf pad => OOB counts as 1):
//   vert  = rowAbove & row & rowBelow        (OOB row = all-ones)
//   erode = vert & shl1(vert) & shr1(vert)   (OOB col carry-in = 1)
//   edge  = row & ~erode                     (erode subset of row)
// Row popcounts -> block inclusive scan -> each thread writes its row's
// points in column order at its exclusive prefix (row-major global order,
// identical to jnp.nonzero). Truncate at KE, store FULL count (divisor).
// ---------------------------------------------------------------------------
__global__ void __launch_bounds__(256) edge_compact2(
        const u64* __restrict__ bm,
        float2* __restrict__ gpts, float2* __restrict__ ppts,
        int* __restrict__ gcnt, int* __restrict__ pcnt) {
    int b = blockIdx.x;                 // 0..31
    int tensor = b >> 4;
    int slice = b & 15;
    const u64* rm = bm + (size_t)(tensor * 4096 + slice * 256) * 4;
    float2* pts = (tensor ? ppts : gpts) + slice * KE;
    int* cnt = (tensor ? pcnt : gcnt) + slice;

    int row = threadIdx.x;
    u64 vc[4], va[4], vb[4];
#pragma unroll
    for (int w = 0; w < 4; ++w) {
        vc[w] = rm[row * 4 + w];
        va[w] = (row > 0) ? rm[(row - 1) * 4 + w] : ~0ull;
        vb[w] = (row < HH - 1) ? rm[(row + 1) * 4 + w] : ~0ull;
    }
    u64 vert[4];
#pragma unroll
    for (int w = 0; w < 4; ++w) vert[w] = va[w] & vc[w] & vb[w];
    u64 e[4];
#pragma unroll
    for (int w = 0; w < 4; ++w) {
        u64 left  = (vert[w] << 1) | ((w > 0) ? (vert[w - 1] >> 63) : 1ull);
        u64 right = (vert[w] >> 1) | (((w < 3) ? (vert[w + 1] & 1ull) : 1ull) << 63);
        e[w] = vc[w] & ~(vert[w] & left & right);
    }
    int mycnt = __popcll(e[0]) + __popcll(e[1]) + __popcll(e[2]) + __popcll(e[3]);

    __shared__ int sc[256];
    sc[row] = mycnt;
    __syncthreads();
    for (int d = 1; d < 256; d <<= 1) {
        int v = (row >= d) ? sc[row - d] : 0;
        __syncthreads();
        sc[row] += v;
        __syncthreads();
    }
    int off = sc[row] - mycnt;          // exclusive prefix
#pragma unroll
    for (int w = 0; w < 4; ++w) {
        u64 bits = e[w];
        while (bits) {
            int l = __ffsll((long long)bits) - 1;
            bits &= bits - 1;
            if (off < KE) pts[off] = make_float2((float)row, (float)(w * 64 + l));
            ++off;
        }
    }
    if (row == HH - 1) *cnt = sc[HH - 1];
}

// ---------------------------------------------------------------------------
// Kernel 3: bidirectional nearest-neighbor distance partial sums.
// 512 blocks = 16 slices x 2 dirs x 16 query chunks of 256. Targets staged
// in LDS (broadcast reads, conflict-free); 4-way unrolled independent min
// chains; sqrt once at the end (min of sqrt == sqrt of min).
// ---------------------------------------------------------------------------
__global__ void __launch_bounds__(256) mindist(
        const float2* __restrict__ gpts, const float2* __restrict__ ppts,
        const int* __restrict__ gcnt, const int* __restrict__ pcnt,
        float* __restrict__ gpart, float* __restrict__ ppart) {
    int b = blockIdx.x;                 // 0..511
    int slice = b >> 5;
    int dir = (b >> 4) & 1;             // 0: g->p, 1: p->g
    int qblk = b & 15;

    int qfull = dir ? pcnt[slice] : gcnt[slice];
    int tfull = dir ? gcnt[slice] : pcnt[slice];
    float* part = (dir ? ppart : gpart) + slice * 16 + qblk;
    int tid = threadIdx.x;

    int qc = min(qfull, KE);
    int tc = min(tfull, KE);
    if (qblk * 256 >= qc) {             // nothing to do for this chunk
        if (tid == 0) *part = 0.0f;
        return;
    }

    const float2* q = (dir ? ppts : gpts) + slice * KE;
    const float2* t = (dir ? gpts : ppts) + slice * KE;

    __shared__ float2 tp[KE];
    __shared__ float red[256];
    int tcp = (tc + 3) & ~3;            // pad to x4 with far sentinels
    for (int i = tid; i < tcp; i += 256)
        tp[i] = (i < tc) ? t[i] : make_float2(1e9f, 1e9f);
    __syncthreads();

    int qi = qblk * 256 + tid;
    float val = 0.0f;
    if (qi < qc) {
        float2 qp = q[qi];
        float m0 = INFINITY, m1 = INFINITY, m2 = INFINITY, m3 = INFINITY;
        for (int j = 0; j < tcp; j += 4) {
            float2 t0 = tp[j], t1 = tp[j + 1], t2 = tp[j + 2], t3 = tp[j + 3];
            float dy0 = qp.x - t0.x, dx0 = qp.y - t0.y;
            float dy1 = qp.x - t1.x, dx1 = qp.y - t1.y;
            float dy2 = qp.x - t2.x, dx2 = qp.y - t2.y;
            float dy3 = qp.x - t3.x, dx3 = qp.y - t3.y;
            m0 = fminf(m0, dy0 * dy0 + dx0 * dx0);
            m1 = fminf(m1, dy1 * dy1 + dx1 * dx1);
            m2 = fminf(m2, dy2 * dy2 + dx2 * dx2);
            m3 = fminf(m3, dy3 * dy3 + dx3 * dx3);
        }
        val = sqrtf(fminf(fminf(m0, m1), fminf(m2, m3)));
    }
    red[tid] = val;
    __syncthreads();
    for (int s = 128; s > 0; s >>= 1) {
        if (tid < s) red[tid] += red[tid + s];
        __syncthreads();
    }
    if (tid == 0) *part = red[0];
}

// ---------------------------------------------------------------------------
// Kernel 4: fold partials -> per-slice ahd -> loss -> nanmean.
// Slice contributes NaN (skipped) unless both counts > 0.
// ---------------------------------------------------------------------------
__global__ void finalize(const int* __restrict__ gcnt, const int* __restrict__ pcnt,
                         const float* __restrict__ gpart, const float* __restrict__ ppart,
                         float* __restrict__ out) {
    float sum = 0.0f;
    int nvalid = 0;
    for (int s = 0; s < NSLICE; ++s) {
        int ng = gcnt[s];
        int np_ = pcnt[s];
        if (ng > 0 && np_ > 0) {
            float gs = 0.0f, ps = 0.0f;
            for (int k = 0; k < 16; ++k) {
                gs += gpart[s * 16 + k];
                ps += ppart[s * 16 + k];
            }
            float ahd = 0.5f * (gs / (float)ng + ps / (float)np_);
            sum += 1.0f - 1.0f / (1.0f + ahd);
            nvalid++;
        }
    }
    out[0] = nvalid ? (sum / (float)nvalid) : NAN;
}

// ---------------------------------------------------------------------------
// Workspace layout (bytes):
//   [0,        512K)   gpts : 16 x 4096 float2
//   [512K,     1M)     ppts : 16 x 4096 float2
//   [1M,       1.25M)  bm   : 2 x 16 x 256 x 4 u64  (256 KB)
//   [1310720, +64)     gcnt : 16 int
//   [1310784, +64)     pcnt : 16 int
//   [1310848, +1K)     gpart: 16 x 16 float
//   [1311872, +1K)     ppart: 16 x 16 float
// ---------------------------------------------------------------------------
extern "C" void kernel_launch(void* const* d_in, const int* in_sizes, int n_in,
                              void* d_out, int out_size, void* d_ws, size_t ws_size,
                              hipStream_t stream) {
    const float* gth = (const float*)d_in[0];
    const float* pred = (const float*)d_in[1];
    float* out = (float*)d_out;
    char* ws = (char*)d_ws;

    float2* gpts = (float2*)(ws);
    float2* ppts = (float2*)(ws + 524288);
    u64* bm = (u64*)(ws + 1048576);
    int* gcnt = (int*)(ws + 1310720);
    int* pcnt = (int*)(ws + 1310784);
    float* gpart = (float*)(ws + 1310848);
    float* ppart = (float*)(ws + 1311872);

    binarize_pack<<<8192, 256, 0, stream>>>(gth, pred, bm);
    edge_compact2<<<32, 256, 0, stream>>>(bm, gpts, ppts, gcnt, pcnt);
    mindist<<<512, 256, 0, stream>>>(gpts, ppts, gcnt, pcnt, gpart, ppart);
    finalize<<<1, 1, 0, stream>>>(gcnt, pcnt, gpart, ppart, out);
}